// Round 8
// baseline (517.374 us; speedup 1.0000x reference)
//
#include <hip/hip_runtime.h>
#include <cstdint>
#include <cstddef>

#define FEATURE_IN 4096
#define FEATURE_OUT 4096
#define RNK 16

typedef __bf16 bf16x8_t __attribute__((ext_vector_type(8)));
typedef __bf16 bf16x4_t __attribute__((ext_vector_type(4)));
typedef float f32x4_t __attribute__((ext_vector_type(4)));

// ================= prep_all: one dispatch, two roles (FROZEN, r3/r4/r7 version) =====
// blocks [0, NFUSE)          : Wf[n,k] = bf16(W[n,k] + 2*sum_r A[k,r]*B[r,n])
// blocks [NFUSE, NFUSE+NCVTB): x fp32 -> bf16 (grid-stride, coalesced)
// Kept MERGED and byte-identical so that, with the GEMM split into two ~120 us
// halves, this (~255 us if real) becomes the longest dispatch and finally
// surfaces in the rocprof top-5 with readable counters.
#define FW_KB 128
#define FW_NB 32
#define NFUSE 4096            // (K/FW_KB)*(N/FW_NB) = 32*128
#define NCVTB 2048
#define CVT_THREADS (NCVTB * 256)                   // 524288
#define CVT_CHUNKS 16                               // 8388608 float4s total

__global__ __launch_bounds__(256) void prep_all(const float* __restrict__ x,
                                                uint16_t* __restrict__ xb,
                                                const float* __restrict__ w,
                                                const float* __restrict__ la,
                                                const float* __restrict__ lb,
                                                uint16_t* __restrict__ wf) {
    __shared__ float las[FW_KB * RNK];     // [k][r], 8 KB
    __shared__ float lbs[RNK * FW_NB];     // [r][n], 2 KB

    const int tid = threadIdx.x;

    if (blockIdx.x >= NFUSE) {
        // ---- convert role ----
        const int tg = (blockIdx.x - NFUSE) * 256 + tid;
        const f32x4_t* xp = (const f32x4_t*)x;
        bf16x4_t* op = (bf16x4_t*)xb;
#pragma unroll
        for (int i = 0; i < CVT_CHUNKS; ++i) {
            const int idx = i * CVT_THREADS + tg;
            f32x4_t v = xp[idx];
            bf16x4_t o;
            o[0] = (__bf16)v[0]; o[1] = (__bf16)v[1];
            o[2] = (__bf16)v[2]; o[3] = (__bf16)v[3];
            op[idx] = o;
        }
        return;
    }

    // ---- fuse role ----
    const int bid = blockIdx.x;
    const int kb = (bid & 31) * FW_KB;
    const int nb = (bid >> 5) * FW_NB;

    {
        const float4* src = (const float4*)(la + (size_t)kb * RNK);
        float4* dst = (float4*)las;
        dst[tid] = src[tid];
        dst[tid + 256] = src[tid + 256];
    }
#pragma unroll
    for (int f = tid; f < RNK * FW_NB; f += 256) {
        int r = f >> 5;
        int nl = f & 31;
        lbs[r * FW_NB + nl] = lb[(size_t)r * FEATURE_OUT + nb + nl];
    }
    __syncthreads();

    const int nl = tid >> 3;    // 0..31
    const int kq = tid & 7;     // 0..7, each covers 16 k

    f32x4_t bcol[4];
#pragma unroll
    for (int r4 = 0; r4 < 4; ++r4) {
        f32x4_t v;
#pragma unroll
        for (int j = 0; j < 4; ++j) v[j] = lbs[(r4 * 4 + j) * FW_NB + nl];
        bcol[r4] = v;
    }

    const f32x4_t* las4 = (const f32x4_t*)las;   // index k*4 + r4
    const float* wrow = w + (size_t)(nb + nl) * FEATURE_IN + kb + kq * 16;
    uint16_t* wfrow = wf + (size_t)(nb + nl) * FEATURE_IN + kb + kq * 16;

#pragma unroll
    for (int h = 0; h < 2; ++h) {          // two groups of 8 k
        float4 wv0 = ((const float4*)wrow)[h * 2 + 0];
        float4 wv1 = ((const float4*)wrow)[h * 2 + 1];
        float wfv[8] = {wv0.x, wv0.y, wv0.z, wv0.w, wv1.x, wv1.y, wv1.z, wv1.w};
        bf16x8_t o;
#pragma unroll
        for (int j = 0; j < 8; ++j) {
            const int k = kq * 16 + h * 8 + j;
            float s = 0.f;
#pragma unroll
            for (int rr = 0; rr < 4; ++rr) {
                const int r4 = (rr + kq) & 3;
                f32x4_t av = las4[k * 4 + r4];
                f32x4_t bv = bcol[r4];
                s += av[0] * bv[0] + av[1] * bv[1] + av[2] * bv[2] + av[3] * bv[3];
            }
            o[j] = (__bf16)(wfv[j] + 2.f * s);
        }
        ((bf16x8_t*)wfrow)[h] = o;
    }
}

// ====== GEMM: 256x256, BK=32, 4-buffer stage-3-ahead, reg-pipelined (r4 BEST) ======
// r4's proven-best schedule (239.5 us full-grid, MfmaUtil 53%), verbatim except for
// an mOff parameter: launched as TWO m-half dispatches (grid 16x16 = 256 blocks
// each, exactly 1 block/CU) so prep_all can surface in the rocprof top-5.
// Per tile t: P0 {READ_AFY(t) || STAGE_A(t+3) || MFMA-X} VMCNT(6) BAR
//             P1 {READ_R0(t+1) || STAGE_B(t+3) || MFMA-Y} BAR
#define BM 256
#define BN 256
#define BK 32
#define NT (FEATURE_IN / BK)   // 128 K-tiles

#define ABUF(b) ((b) * 32768)
#define BBUF(b) ((b) * 32768 + 16384)

#define MFMA16X(S) do { _Pragma("unroll")                                                \
    for (int _mi = 0; _mi < 4; ++_mi) { _Pragma("unroll")                                \
        for (int _ni = 0; _ni < 4; ++_ni)                                                \
            acc[_mi][_ni] = __builtin_amdgcn_mfma_f32_16x16x32_bf16(                     \
                afx[S][_mi], bqr[S][_ni], acc[_mi][_ni], 0, 0, 0); } } while (0)

#define MFMA16Y(S) do { _Pragma("unroll")                                                \
    for (int _mi = 0; _mi < 4; ++_mi) { _Pragma("unroll")                                \
        for (int _ni = 0; _ni < 4; ++_ni)                                                \
            acc[4 + _mi][_ni] = __builtin_amdgcn_mfma_f32_16x16x32_bf16(                 \
                afy[_mi], bqr[S][_ni], acc[4 + _mi][_ni], 0, 0, 0); } } while (0)

#define READ_AFY(b) do { _Pragma("unroll")                                               \
    for (int _mi = 0; _mi < 4; ++_mi)                                                    \
        afy[_mi] = *(const bf16x8_t*)(lds + ABUF(b) + aoff[4 + _mi]); } while (0)

#define READ_R0(b, SN) do { _Pragma("unroll")                                            \
    for (int _mi = 0; _mi < 4; ++_mi)                                                    \
        afx[SN][_mi] = *(const bf16x8_t*)(lds + ABUF(b) + aoff[_mi]);                    \
    _Pragma("unroll")                                                                    \
    for (int _ni = 0; _ni < 4; ++_ni)                                                    \
        bqr[SN][_ni] = *(const bf16x8_t*)(lds + BBUF(b) + boff[_ni]); } while (0)

#define GLL(SRC, DSTOFF)                                                                 \
    __builtin_amdgcn_global_load_lds(                                                    \
        (const __attribute__((address_space(1))) void*)(SRC),                            \
        (__attribute__((address_space(3))) void*)(lds + (DSTOFF) + wv * 1024), 16, 0, 0)

#define STAGE_A(b) do { GLL(pA0, ABUF(b)); GLL(pA1, ABUF(b) + 8192);                     \
                        pA0 += BK; pA1 += BK; } while (0)
#define STAGE_B(b) do { GLL(pB0, BBUF(b)); GLL(pB1, BBUF(b) + 8192);                     \
                        pB0 += BK; pB1 += BK; } while (0)

#define PBAR() __builtin_amdgcn_s_barrier()
#define PRIO1 __builtin_amdgcn_s_setprio(1)
#define PRIO0 __builtin_amdgcn_s_setprio(0)
#define VMCNT(n) asm volatile("s_waitcnt vmcnt(" #n ")" ::: "memory")
#define SCHEDB() __builtin_amdgcn_sched_barrier(0)

// Tile t in buf CUR (parity set S), staging tile t+3 into buf NXT.
#define TILE_BODY(CUR, NXT, S, SN)                                                       \
    READ_AFY(CUR);                                                                       \
    STAGE_A(NXT);                                                                        \
    SCHEDB();                                                                            \
    PRIO1; MFMA16X(S); PRIO0;                                                            \
    VMCNT(6);                                                                            \
    PBAR();                                                                              \
    READ_R0((CUR + 1) & 3, SN);                                                          \
    STAGE_B(NXT);                                                                        \
    SCHEDB();                                                                            \
    PRIO1; MFMA16Y(S); PRIO0;                                                            \
    PBAR();

// Tail tile (no staging): NWAIT counted to retire exactly tile t+1's loads.
#define TAIL_BODY(CUR, S, SN, NWAIT)                                                     \
    READ_AFY(CUR);                                                                       \
    SCHEDB();                                                                            \
    PRIO1; MFMA16X(S); PRIO0;                                                            \
    VMCNT(NWAIT);                                                                        \
    PBAR();                                                                              \
    READ_R0((CUR + 1) & 3, SN);                                                          \
    SCHEDB();                                                                            \
    PRIO1; MFMA16Y(S); PRIO0;                                                            \
    PBAR();

__global__ __launch_bounds__(512, 2) void gemm256(const uint16_t* __restrict__ Au,
                                                  const uint16_t* __restrict__ Bu,
                                                  const float* __restrict__ bias,
                                                  float* __restrict__ C,
                                                  int M, int N, int K, int mOff) {
    __shared__ __align__(16) char lds[131072];   // 4 bufs x (A 16K | B 16K)

    const __bf16* A = (const __bf16*)Au;
    const __bf16* B = (const __bf16*)Bu;

    const int tid  = threadIdx.x;
    const int wv   = tid >> 6;          // 0..7
    const int lane = tid & 63;
    const int waveM = wv >> 2;          // 0..1
    const int waveN = wv & 3;           // 0..3
    const int l15 = lane & 15;
    const int q   = lane >> 4;          // fragment k-chunk 0..3

    // T1: bijective XCD-chunk swizzle (nwg=256 per half-dispatch, 256%8==0)
    const int nbx = N / BN;
    const int nwg = nbx * gridDim.y;
    const int bidlin = blockIdx.y * nbx + blockIdx.x;
    const int swz = (bidlin & 7) * (nwg >> 3) + (bidlin >> 3);
    const int by = swz / nbx;
    const int bx = swz - by * nbx;
    const int m0 = mOff + by * BM;
    const int n0 = bx * BN;

    // staging source mapping (chunk c -> row c>>2, phys slot c&3)
    const int srow = tid >> 2;
    const int sq   = ((tid & 3) - (srow >> 1)) & 3;
    const __bf16* pA0 = A + (size_t)(m0 + srow) * K + sq * 8;
    const __bf16* pA1 = pA0 + (size_t)128 * K;
    const __bf16* pB0 = B + (size_t)(n0 + srow) * K + sq * 8;
    const __bf16* pB1 = pB0 + (size_t)128 * K;

    // per-thread fragment LDS byte offsets (within a 16 KB tile block)
    int aoff[8], boff[4];
#pragma unroll
    for (int mi = 0; mi < 8; ++mi) {
        int row = waveM * 128 + mi * 16 + l15;
        aoff[mi] = row * 64 + (((row >> 1) + q) & 3) * 16;
    }
#pragma unroll
    for (int ni = 0; ni < 4; ++ni) {
        int row = waveN * 64 + ni * 16 + l15;
        boff[ni] = row * 64 + (((row >> 1) + q) & 3) * 16;
    }

    f32x4_t acc[8][4];
#pragma unroll
    for (int mi = 0; mi < 8; ++mi)
#pragma unroll
        for (int ni = 0; ni < 4; ++ni)
            acc[mi][ni] = (f32x4_t)0.f;

    // fragment register sets: afx/bqr double-buffered by tile parity, afy single
    bf16x8_t afx[2][4], afy[4], bqr[2][4];

    // ---- prologue: stage tiles 0,1,2 (12 loads/wave); publish buf0; prime R0(0) ----
    STAGE_A(0); STAGE_B(0);
    STAGE_A(1); STAGE_B(1);
    STAGE_A(2); STAGE_B(2);
    VMCNT(8);   // retire tile 0's 4 loads
    PBAR();
    READ_R0(0, 0);   // prime set0 with tile 0's fragments

    // ---- main: t=0..123 (stage tiles 3..126), parity = t&1 ----
#pragma unroll 1
    for (int i = 0; i < 31; ++i) {
        TILE_BODY(0, 3, 0, 1)
        TILE_BODY(1, 0, 1, 0)
        TILE_BODY(2, 1, 0, 1)
        TILE_BODY(3, 2, 1, 0)
    }
    // t=124 (buf0, set0): stages tile 127 into buf3
    TILE_BODY(0, 3, 0, 1)

    // ---- drain: t=125 (buf1,set1), t=126 (buf2,set0) ----
    TAIL_BODY(1, 1, 0, 4)    // VMCNT(4): retires tile 126's pair
    TAIL_BODY(2, 0, 1, 0)    // VMCNT(0): retires tile 127's pair
    // t=127 (buf3, set1)
    READ_AFY(3);
    SCHEDB();
    PRIO1; MFMA16X(1); PRIO0;
    PRIO1; MFMA16Y(1); PRIO0;

    // ---- C write: D layout col=lane&15, row=q*4+j ----
#pragma unroll
    for (int ni = 0; ni < 4; ++ni) {
        const int col = n0 + waveN * 64 + ni * 16 + l15;
        const float bv = bias[col];
#pragma unroll
        for (int mi = 0; mi < 8; ++mi) {
            const int row = m0 + waveM * 128 + mi * 16 + q * 4;
            float* op = C + (size_t)row * N + col;
#pragma unroll
            for (int j = 0; j < 4; ++j)
                op[(size_t)j * N] = acc[mi][ni][j] + bv;
        }
    }
}

extern "C" void kernel_launch(void* const* d_in, const int* in_sizes, int n_in,
                              void* d_out, int out_size, void* d_ws, size_t ws_size,
                              hipStream_t stream) {
    const float* x  = (const float*)d_in[0];   // [4,2048,4096]
    const float* w  = (const float*)d_in[1];   // [4096,4096]  (out,in)
    const float* b  = (const float*)d_in[2];   // [4096]
    const float* la = (const float*)d_in[3];   // [4096,16]
    const float* lb = (const float*)d_in[4];   // [16,4096]
    float* out = (float*)d_out;

    const int M = in_sizes[0] / FEATURE_IN;    // 8192
    const int K = FEATURE_IN;
    const int N = FEATURE_OUT;

    uint16_t* xb = (uint16_t*)d_ws;                                  // M*K bf16 = 64 MiB
    uint16_t* wf = (uint16_t*)((char*)d_ws + (size_t)M * K * 2);     // N*K bf16 = 32 MiB

    // 1) prep: x->bf16 + LoRA-folded W->bf16 (single dispatch, both roles)
    prep_all<<<NFUSE + NCVTB, 256, 0, stream>>>(x, xb, w, la, lb, wf);

    // 2) GEMM + bias: r4 schedule, split into two m-half dispatches (256 blocks
    //    each = 1 block/CU) so prep_all surfaces in the profiling top-5.
    {
        dim3 grid(N / BN, (M / BM) / 2);   // (16, 16)
        gemm256<<<grid, 512, 0, stream>>>(xb, wf, b, out, M, N, K, 0);
        gemm256<<<grid, 512, 0, stream>>>(xb, wf, b, out, M, N, K, M / 2);
    }
}